// Round 14
// baseline (214.975 us; speedup 1.0000x reference)
//
#include <hip/hip_runtime.h>
#include <hip/hip_cooperative_groups.h>

namespace cg = cooperative_groups;

#define C_IN   512
#define C_INT  128
#define NBUCK  8192
#define NSEG   256             // bucket-aligned segments
#define BPS    (NBUCK / NSEG)  // 32 buckets per segment

typedef short short8 __attribute__((ext_vector_type(8)));
typedef float floatx4 __attribute__((ext_vector_type(4)));

// ---------- helpers ----------

__device__ __forceinline__ int bucket_of(float v, float bmin, float inv_w) {
    float fk = (v - bmin) * inv_w;
    fk = fminf(fmaxf(fk, 0.f), (float)(NBUCK - 1));
    return (int)fk;
}

__device__ __forceinline__ short bf16rnd(float v) {
    unsigned u = __float_as_uint(v);
    return (short)((u + 0x7fffu + ((u >> 16) & 1u)) >> 16);
}

// ---------- K1: prep (verified r5/r11, unchanged) ----------

__global__ __launch_bounds__(256) void prep_kernel(
        const float* __restrict__ Wt, const float* __restrict__ Wp,
        const float* __restrict__ Wg, const float* __restrict__ wcat,
        const float* __restrict__ bt, const float* __restrict__ bp,
        float* __restrict__ ut, float* __restrict__ up, float* __restrict__ scal,
        unsigned short* __restrict__ WgT) {
    int t = threadIdx.x, bk = blockIdx.x;
    if (bk < 16) {
        const float* W  = (bk < 8) ? Wt : Wp;
        const float* wv = wcat + ((bk < 8) ? 0 : C_INT);
        float* dst      = (bk < 8) ? ut : up;
        int k = (bk & 7) * 64 + (t >> 2);
        int q = t & 3;
        const float4* row = (const float4*)(W + (size_t)k * C_INT);
        const float4* cv4 = (const float4*)wv;
        float s = 0.f;
        #pragma unroll
        for (int i = 0; i < 8; ++i) {
            float4 a = row[q * 8 + i];
            float4 c = cv4[q * 8 + i];
            s += a.x * c.x + a.y * c.y + a.z * c.z + a.w * c.w;
        }
        s += __shfl_xor(s, 1);
        s += __shfl_xor(s, 2);
        if (q == 0) dst[k] = s;
    } else if (bk == 16) {
        float s1p = (t < C_INT) ? bt[t] * wcat[t] : 0.f;
        float s2p = (t < C_INT) ? bp[t] * wcat[C_INT + t] : 0.f;
        for (int off = 32; off; off >>= 1) {
            s1p += __shfl_down(s1p, off);
            s2p += __shfl_down(s2p, off);
        }
        __shared__ float red[8];
        int w = t >> 6, lane = t & 63;
        if (lane == 0) { red[w] = s1p; red[4 + w] = s2p; }
        __syncthreads();
        if (t == 0) {
            scal[0] = red[0] + red[1] + red[2] + red[3];
            scal[1] = red[4] + red[5] + red[6] + red[7];
        }
    } else {
        __shared__ float tile[64][132];
        int kb = (bk - 17) * 64;
        #pragma unroll
        for (int it = 0; it < 8; ++it) {
            int idx = it * 256 + t;
            int r = idx >> 5, c4 = idx & 31;
            *(float4*)&tile[r][c4 * 4] =
                ((const float4*)(Wg + (size_t)(kb + r) * C_INT))[c4];
        }
        __syncthreads();
        int n = t & 127, kc = (t >> 7) * 32;
        unsigned pk[16];
        #pragma unroll
        for (int i = 0; i < 16; ++i) {
            unsigned lo = (unsigned short)bf16rnd(tile[kc + 2 * i][n]);
            unsigned hi = (unsigned short)bf16rnd(tile[kc + 2 * i + 1][n]);
            pk[i] = lo | (hi << 16);
        }
        uint4* dst = (uint4*)(WgT + (size_t)n * C_IN + kb + kc);
        #pragma unroll
        for (int i2 = 0; i2 < 4; ++i2) dst[i2] = *(uint4*)&pk[i2 * 4];
    }
}

// ---------- K2: MFMA gemm, col-split (verified r11, unchanged) ----------

#define RSTR 66

__global__ __launch_bounds__(256) void gemm_mfma(
        const float* __restrict__ x, const unsigned short* __restrict__ WgT,
        const float* __restrict__ bg,
        const float* __restrict__ ut, const float* __restrict__ up,
        const float* __restrict__ scal,
        _Float16* __restrict__ g, float* __restrict__ a, float* __restrict__ b) {
    __shared__ float red[3][20][RSTR];
    int tid = threadIdx.x;
    int lane = tid & 63, wv = tid >> 6;
    int bx = blockIdx.x;
    int i0 = (bx >> 1) * 16;
    int cg0 = bx & 1;
    int m = lane & 15, q = lane >> 4;
    floatx4 accg[4] = {};
    floatx4 accab = {};
    const float* xrow = x + (size_t)(i0 + m) * C_IN + q * 8;
    const float* absrc = (m == 0) ? ut : up;
    #pragma unroll
    for (int ks = 0; ks < 4; ++ks) {
        int k0 = (wv * 4 + ks) * 32;
        float4 f0 = *(const float4*)(xrow + k0);
        float4 f1 = *(const float4*)(xrow + k0 + 4);
        short8 af;
        af[0] = bf16rnd(f0.x); af[1] = bf16rnd(f0.y);
        af[2] = bf16rnd(f0.z); af[3] = bf16rnd(f0.w);
        af[4] = bf16rnd(f1.x); af[5] = bf16rnd(f1.y);
        af[6] = bf16rnd(f1.z); af[7] = bf16rnd(f1.w);
        if (cg0 == 0) {
            short8 abf = {};
            if (m < 2) {
                float4 u0 = *(const float4*)(absrc + k0 + q * 8);
                float4 u1 = *(const float4*)(absrc + k0 + q * 8 + 4);
                abf[0] = bf16rnd(u0.x); abf[1] = bf16rnd(u0.y);
                abf[2] = bf16rnd(u0.z); abf[3] = bf16rnd(u0.w);
                abf[4] = bf16rnd(u1.x); abf[5] = bf16rnd(u1.y);
                abf[6] = bf16rnd(u1.z); abf[7] = bf16rnd(u1.w);
            }
            accab = __builtin_amdgcn_mfma_f32_16x16x32_bf16(af, abf, accab, 0, 0, 0);
        }
        #pragma unroll
        for (int f = 0; f < 4; ++f) {
            short8 bfr = *(const short8*)(WgT + (size_t)(cg0 * 64 + f * 16 + m) * C_IN + k0 + q * 8);
            accg[f] = __builtin_amdgcn_mfma_f32_16x16x32_bf16(af, bfr, accg[f], 0, 0, 0);
        }
    }
    if (wv) {
        #pragma unroll
        for (int f = 0; f < 4; ++f)
            #pragma unroll
            for (int r = 0; r < 4; ++r)
                red[wv - 1][f * 4 + r][lane] = accg[f][r];
        #pragma unroll
        for (int r = 0; r < 4; ++r)
            red[wv - 1][16 + r][lane] = accab[r];
    }
    __syncthreads();
    if (wv == 0) {
        #pragma unroll
        for (int w = 0; w < 3; ++w) {
            #pragma unroll
            for (int f = 0; f < 4; ++f)
                #pragma unroll
                for (int r = 0; r < 4; ++r)
                    accg[f][r] += red[w][f * 4 + r][lane];
            #pragma unroll
            for (int r = 0; r < 4; ++r)
                accab[r] += red[w][16 + r][lane];
        }
        #pragma unroll
        for (int f = 0; f < 4; ++f) {
            int col = cg0 * 64 + f * 16 + m;
            float bgv = bg[col];
            #pragma unroll
            for (int r = 0; r < 4; ++r) {
                int row = i0 + q * 4 + r;
                g[(size_t)row * C_INT + col] = (_Float16)(accg[f][r] + bgv);
            }
        }
        if (cg0 == 0 && m < 2) {
            float off = m ? scal[1] : scal[0];
            float* dst = m ? b : a;
            #pragma unroll
            for (int r = 0; r < 4; ++r) dst[i0 + q * 4 + r] = accab[r] + off;
        }
    }
}

// ---------- K3: cooperative mega: sort+segsum -> suffix+Pr -> out ----------
// 256 blocks x 1024 thr (1 block/CU guaranteed co-resident), 2x grid.sync().

__global__ __launch_bounds__(1024) void mega_kernel(
        const _Float16* __restrict__ g, const float* __restrict__ b,
        const float* __restrict__ a,
        unsigned* __restrict__ offs_g, unsigned short* __restrict__ perm_g,
        float* __restrict__ bsort_g,
        float* __restrict__ seg1, float* __restrict__ seg2,
        float* __restrict__ Pr1, float* __restrict__ Pr2,
        float* __restrict__ out, float inv_n) {
    cg::grid_group grid = cg::this_grid();
    __shared__ unsigned oh[NBUCK / 2];     // packed u16 pairs: hist -> incl scan
    __shared__ unsigned cur[NBUCK / 2];
    __shared__ unsigned short ls[8192];
    __shared__ unsigned wtu[16];
    __shared__ float smn[16], smx[16];
    __shared__ float part1[8][128], part2[8][128];
    int t = threadIdx.x, s = blockIdx.x;
    int lane = t & 63, wv = t >> 6;
    int c = t & 127, p = t >> 7;

    // ===== phase 1: self-sort (r13-verified) + own-segment sums =====
    #pragma unroll
    for (int r = 0; r < 4; ++r) { oh[t + r * 1024] = 0u; cur[t + r * 1024] = 0u; }
    float bv[8];
    float mn = 1e30f, mx = -1e30f;
    #pragma unroll
    for (int r = 0; r < 8; ++r) {
        bv[r] = b[t + r * 1024];
        mn = fminf(mn, bv[r]); mx = fmaxf(mx, bv[r]);
    }
    for (int off = 32; off; off >>= 1) {
        mn = fminf(mn, __shfl_down(mn, off));
        mx = fmaxf(mx, __shfl_down(mx, off));
    }
    if (lane == 0) { smn[wv] = mn; smx[wv] = mx; }
    __syncthreads();
    if (t == 0) {
        float gmn = smn[0], gmx = smx[0];
        #pragma unroll
        for (int i = 1; i < 16; ++i) {
            gmn = fminf(gmn, smn[i]); gmx = fmaxf(gmx, smx[i]);
        }
        float range = gmx - gmn;
        float iw = (range > 1e-30f) ? (float)NBUCK / range : 0.f;
        smn[0] = gmn; smx[0] = iw;
    }
    __syncthreads();
    float bmin = smn[0], inv_w = smx[0];   // registers; identical in every block
    int kb[8];
    #pragma unroll
    for (int r = 0; r < 8; ++r) {
        kb[r] = bucket_of(bv[r], bmin, inv_w);
        atomicAdd(&oh[kb[r] >> 1], (kb[r] & 1) ? 0x10000u : 1u);
    }
    __syncthreads();
    unsigned h[8], p0 = 0;
    #pragma unroll
    for (int w = 0; w < 4; ++w) {
        unsigned word = oh[t * 4 + w];
        p0 += word & 0xffffu;  h[w * 2]     = p0;
        p0 += word >> 16;      h[w * 2 + 1] = p0;
    }
    unsigned v = p0;
    #pragma unroll
    for (int d = 1; d < 64; d <<= 1) {
        unsigned u = __shfl_up(v, d);
        if (lane >= d) v += u;
    }
    if (lane == 63) wtu[wv] = v;
    __syncthreads();
    if (t < 16) {
        unsigned w = wtu[t];
        #pragma unroll
        for (int d = 1; d < 16; d <<= 1) {
            unsigned u = __shfl_up(w, d);
            if (t >= d) w += u;
        }
        wtu[t] = w;
    }
    __syncthreads();
    unsigned base = (v - p0) + (wv ? wtu[wv - 1] : 0u);
    #pragma unroll
    for (int w = 0; w < 4; ++w) {
        unsigned lo = base + h[w * 2], hi = base + h[w * 2 + 1];
        oh[t * 4 + w] = lo | (hi << 16);
        if (s == 0) {
            offs_g[t * 8 + w * 2 + 1] = lo;
            offs_g[t * 8 + w * 2 + 2] = hi;
        }
    }
    if (s == 0 && t == 0) offs_g[0] = 0u;
    __syncthreads();
    #pragma unroll
    for (int r = 0; r < 8; ++r) {
        int j = t + r * 1024;
        int k = kb[r];
        unsigned st = 0u;
        if (k > 0) {
            unsigned word = oh[(k - 1) >> 1];
            st = ((k - 1) & 1) ? (word >> 16) : (word & 0xffffu);
        }
        unsigned old = atomicAdd(&cur[k >> 1], (k & 1) ? 0x10000u : 1u);
        unsigned pos = (k & 1) ? (old >> 16) : (old & 0xffffu);
        ls[st + pos] = (unsigned short)j;
    }
    __syncthreads();
    auto incl = [&](int kk) -> unsigned {
        unsigned word = oh[kk >> 1];
        return (kk & 1) ? (word >> 16) : (word & 0xffffu);
    };
    unsigned E0 = (s == 0) ? 0u : incl(s * BPS - 1);
    unsigned E1 = incl((s + 1) * BPS - 1);
    // publish own slice of perm/bsort
    for (unsigned e = E0 + t; e < E1; e += 1024) {
        int j = ls[e];
        perm_g[e] = (unsigned short)j;
        bsort_g[e] = b[j];
    }
    // own-segment sums, 8 parts x 128 channels
    {
        float a1 = 0.f, a2 = 0.f;
        for (unsigned e = E0 + p; e < E1; e += 8) {
            int j = ls[e];
            float gv = (float)g[(size_t)j * C_INT + c];
            a1 += gv; a2 += b[j] * gv;
        }
        part1[p][c] = a1; part2[p][c] = a2;
        __syncthreads();
        if (p == 0) {
            float t1 = 0.f, t2 = 0.f;
            #pragma unroll
            for (int pp = 0; pp < 8; ++pp) { t1 += part1[pp][c]; t2 += part2[pp][c]; }
            seg1[s * C_INT + c] = t1;
            seg2[s * C_INT + c] = t2;
        }
    }
    grid.sync();

    // ===== phase 2: seg-suffix (8-way) + serial walk own segment -> Pr =====
    {
        float r1 = 0.f, r2 = 0.f;
        for (int s2 = s + 1 + p; s2 < NSEG; s2 += 8) {
            r1 += seg1[s2 * C_INT + c];
            r2 += seg2[s2 * C_INT + c];
        }
        part1[p][c] = r1; part2[p][c] = r2;
    }
    __syncthreads();
    if (t < 128) {
        float w1 = 0.f, w2 = 0.f;
        #pragma unroll
        for (int pp = 0; pp < 8; ++pp) { w1 += part1[pp][t]; w2 += part2[pp][t]; }
        for (int e = (int)E1 - 1; e >= (int)E0; --e) {
            int j = ls[e];
            float gv = (float)g[(size_t)j * C_INT + t];
            w1 += gv; w2 += b[j] * gv;
            size_t idx = (size_t)e * C_INT + t;
            Pr1[idx] = w1; Pr2[idx] = w2;
        }
        if (s == 0) {
            Pr1[(size_t)8192 * C_INT + t] = 0.f;
            Pr2[(size_t)8192 * C_INT + t] = 0.f;
        }
    }
    grid.sync();

    // ===== phase 3: out — 8 rows in parallel x 4 batches (32 rows/block) =====
    #pragma unroll
    for (int batch = 0; batch < 4; ++batch) {
        int i = s * 32 + batch * 8 + p;
        float ai = a[i], thr = -ai;
        int ki = bucket_of(thr, bmin, inv_w);
        unsigned e0 = offs_g[ki], e1 = offs_g[ki + 1];
        size_t pb = (size_t)e1 * C_INT + c;
        float acc = ai * Pr1[pb] + Pr2[pb];
        for (unsigned e = e0; e < e1; ++e) {        // avg ~1 iter (1 elem/bucket)
            float bj = bsort_g[e];
            if (bj > thr) {
                int j = perm_g[e];
                acc += (ai + bj) * (float)g[(size_t)j * C_INT + c];
            }
        }
        out[(size_t)i * C_INT + c] = acc * inv_n;
    }
}

// ---------- launch ----------

extern "C" void kernel_launch(void* const* d_in, const int* in_sizes, int n_in,
                              void* d_out, int out_size, void* d_ws, size_t ws_size,
                              hipStream_t stream) {
    const float* x    = (const float*)d_in[0];
    const float* Wg   = (const float*)d_in[1];
    const float* bg   = (const float*)d_in[2];
    const float* Wt   = (const float*)d_in[3];
    const float* bt   = (const float*)d_in[4];
    const float* Wp   = (const float*)d_in[5];
    const float* bp   = (const float*)d_in[6];
    const float* wcat = (const float*)d_in[7];
    float* out = (float*)d_out;
    int n = in_sizes[0] / C_IN;   // 8192

    char* w = (char*)d_ws;
    size_t off = 0;
    auto alloc = [&](size_t bytes) -> void* {
        void* p = w + off;
        off += (bytes + 255) & ~(size_t)255;
        return p;
    };
    float*          ut    = (float*)alloc(C_IN * 4);
    float*          up    = (float*)alloc(C_IN * 4);
    float*          scal  = (float*)alloc(32);
    float*          a     = (float*)alloc((size_t)n * 4);
    float*          b     = (float*)alloc((size_t)n * 4);
    unsigned*       offs  = (unsigned*)alloc((size_t)(NBUCK + 1) * 4);
    unsigned short* perm  = (unsigned short*)alloc((size_t)n * 2);
    float*          bsort = (float*)alloc((size_t)n * 4);
    _Float16*       g     = (_Float16*)alloc((size_t)n * C_INT * 2);
    unsigned short* WgT   = (unsigned short*)alloc((size_t)C_INT * C_IN * 2);
    float*          seg1  = (float*)alloc((size_t)NSEG * C_INT * 4);
    float*          seg2  = (float*)alloc((size_t)NSEG * C_INT * 4);
    float*          Pr1   = (float*)alloc((size_t)(n + 1) * C_INT * 4);
    float*          Pr2   = (float*)alloc((size_t)(n + 1) * C_INT * 4);

    prep_kernel<<<25, 256, 0, stream>>>(Wt, Wp, Wg, wcat, bt, bp, ut, up, scal, WgT);
    gemm_mfma<<<n / 8, 256, 0, stream>>>(x, WgT, bg, ut, up, scal, g, a, b);
    float inv_n = 1.0f / (float)n;
    void* kargs[] = {(void*)&g, (void*)&b, (void*)&a, (void*)&offs, (void*)&perm,
                     (void*)&bsort, (void*)&seg1, (void*)&seg2, (void*)&Pr1,
                     (void*)&Pr2, (void*)&out, (void*)&inv_n};
    hipLaunchCooperativeKernel((void*)mega_kernel, dim3(NSEG), dim3(1024),
                               kargs, 0, stream);
}

// Round 15
// 142.837 us; speedup vs baseline: 1.5050x; 1.5050x over previous
//
#include <hip/hip_runtime.h>

#define C_IN   512
#define C_INT  128
#define NBUCK  8192
#define SEG    32
#define NSEG   256   // 8192 / SEG

typedef short short8 __attribute__((ext_vector_type(8)));
typedef float floatx4 __attribute__((ext_vector_type(4)));

// ---------- helpers ----------

__device__ __forceinline__ int bucket_of(float v, float bmin, float inv_w) {
    float fk = (v - bmin) * inv_w;
    fk = fminf(fmaxf(fk, 0.f), (float)(NBUCK - 1));
    return (int)fk;
}

__device__ __forceinline__ short bf16rnd(float v) {
    unsigned u = __float_as_uint(v);
    return (short)((u + 0x7fffu + ((u >> 16) & 1u)) >> 16);
}

// ---------- K1: prep (verified r5/r11, unchanged) ----------

__global__ __launch_bounds__(256) void prep_kernel(
        const float* __restrict__ Wt, const float* __restrict__ Wp,
        const float* __restrict__ Wg, const float* __restrict__ wcat,
        const float* __restrict__ bt, const float* __restrict__ bp,
        float* __restrict__ ut, float* __restrict__ up, float* __restrict__ scal,
        unsigned short* __restrict__ WgT) {
    int t = threadIdx.x, bk = blockIdx.x;
    if (bk < 16) {
        const float* W  = (bk < 8) ? Wt : Wp;
        const float* wv = wcat + ((bk < 8) ? 0 : C_INT);
        float* dst      = (bk < 8) ? ut : up;
        int k = (bk & 7) * 64 + (t >> 2);
        int q = t & 3;
        const float4* row = (const float4*)(W + (size_t)k * C_INT);
        const float4* cv4 = (const float4*)wv;
        float s = 0.f;
        #pragma unroll
        for (int i = 0; i < 8; ++i) {
            float4 a = row[q * 8 + i];
            float4 c = cv4[q * 8 + i];
            s += a.x * c.x + a.y * c.y + a.z * c.z + a.w * c.w;
        }
        s += __shfl_xor(s, 1);
        s += __shfl_xor(s, 2);
        if (q == 0) dst[k] = s;
    } else if (bk == 16) {
        float s1p = (t < C_INT) ? bt[t] * wcat[t] : 0.f;
        float s2p = (t < C_INT) ? bp[t] * wcat[C_INT + t] : 0.f;
        for (int off = 32; off; off >>= 1) {
            s1p += __shfl_down(s1p, off);
            s2p += __shfl_down(s2p, off);
        }
        __shared__ float red[8];
        int w = t >> 6, lane = t & 63;
        if (lane == 0) { red[w] = s1p; red[4 + w] = s2p; }
        __syncthreads();
        if (t == 0) {
            scal[0] = red[0] + red[1] + red[2] + red[3];
            scal[1] = red[4] + red[5] + red[6] + red[7];
        }
    } else {
        __shared__ float tile[64][132];
        int kb = (bk - 17) * 64;
        #pragma unroll
        for (int it = 0; it < 8; ++it) {
            int idx = it * 256 + t;
            int r = idx >> 5, c4 = idx & 31;
            *(float4*)&tile[r][c4 * 4] =
                ((const float4*)(Wg + (size_t)(kb + r) * C_INT))[c4];
        }
        __syncthreads();
        int n = t & 127, kc = (t >> 7) * 32;
        unsigned pk[16];
        #pragma unroll
        for (int i = 0; i < 16; ++i) {
            unsigned lo = (unsigned short)bf16rnd(tile[kc + 2 * i][n]);
            unsigned hi = (unsigned short)bf16rnd(tile[kc + 2 * i + 1][n]);
            pk[i] = lo | (hi << 16);
        }
        uint4* dst = (uint4*)(WgT + (size_t)n * C_IN + kb + kc);
        #pragma unroll
        for (int i2 = 0; i2 < 4; ++i2) dst[i2] = *(uint4*)&pk[i2 * 4];
    }
}

// ---------- K2: MFMA gemm, col-split (verified r11; +min-waves hint) ----------

#define RSTR 66

__global__ __launch_bounds__(256, 8) void gemm_mfma(
        const float* __restrict__ x, const unsigned short* __restrict__ WgT,
        const float* __restrict__ bg,
        const float* __restrict__ ut, const float* __restrict__ up,
        const float* __restrict__ scal,
        _Float16* __restrict__ g, float* __restrict__ a, float* __restrict__ b) {
    __shared__ float red[3][20][RSTR];
    int tid = threadIdx.x;
    int lane = tid & 63, wv = tid >> 6;
    int bx = blockIdx.x;
    int i0 = (bx >> 1) * 16;
    int cg = bx & 1;
    int m = lane & 15, q = lane >> 4;
    floatx4 accg[4] = {};
    floatx4 accab = {};
    const float* xrow = x + (size_t)(i0 + m) * C_IN + q * 8;
    const float* absrc = (m == 0) ? ut : up;
    #pragma unroll
    for (int ks = 0; ks < 4; ++ks) {
        int k0 = (wv * 4 + ks) * 32;
        float4 f0 = *(const float4*)(xrow + k0);
        float4 f1 = *(const float4*)(xrow + k0 + 4);
        short8 af;
        af[0] = bf16rnd(f0.x); af[1] = bf16rnd(f0.y);
        af[2] = bf16rnd(f0.z); af[3] = bf16rnd(f0.w);
        af[4] = bf16rnd(f1.x); af[5] = bf16rnd(f1.y);
        af[6] = bf16rnd(f1.z); af[7] = bf16rnd(f1.w);
        if (cg == 0) {
            short8 abf = {};
            if (m < 2) {
                float4 u0 = *(const float4*)(absrc + k0 + q * 8);
                float4 u1 = *(const float4*)(absrc + k0 + q * 8 + 4);
                abf[0] = bf16rnd(u0.x); abf[1] = bf16rnd(u0.y);
                abf[2] = bf16rnd(u0.z); abf[3] = bf16rnd(u0.w);
                abf[4] = bf16rnd(u1.x); abf[5] = bf16rnd(u1.y);
                abf[6] = bf16rnd(u1.z); abf[7] = bf16rnd(u1.w);
            }
            accab = __builtin_amdgcn_mfma_f32_16x16x32_bf16(af, abf, accab, 0, 0, 0);
        }
        #pragma unroll
        for (int f = 0; f < 4; ++f) {
            short8 bfr = *(const short8*)(WgT + (size_t)(cg * 64 + f * 16 + m) * C_IN + k0 + q * 8);
            accg[f] = __builtin_amdgcn_mfma_f32_16x16x32_bf16(af, bfr, accg[f], 0, 0, 0);
        }
    }
    if (wv) {
        #pragma unroll
        for (int f = 0; f < 4; ++f)
            #pragma unroll
            for (int r = 0; r < 4; ++r)
                red[wv - 1][f * 4 + r][lane] = accg[f][r];
        #pragma unroll
        for (int r = 0; r < 4; ++r)
            red[wv - 1][16 + r][lane] = accab[r];
    }
    __syncthreads();
    if (wv == 0) {
        #pragma unroll
        for (int w = 0; w < 3; ++w) {
            #pragma unroll
            for (int f = 0; f < 4; ++f)
                #pragma unroll
                for (int r = 0; r < 4; ++r)
                    accg[f][r] += red[w][f * 4 + r][lane];
            #pragma unroll
            for (int r = 0; r < 4; ++r)
                accab[r] += red[w][16 + r][lane];
        }
        #pragma unroll
        for (int f = 0; f < 4; ++f) {
            int col = cg * 64 + f * 16 + m;
            float bgv = bg[col];
            #pragma unroll
            for (int r = 0; r < 4; ++r) {
                int row = i0 + q * 4 + r;
                g[(size_t)row * C_INT + col] = (_Float16)(accg[f][r] + bgv);
            }
        }
        if (cg == 0 && m < 2) {
            float off = m ? scal[1] : scal[0];
            float* dst = m ? b : a;
            #pragma unroll
            for (int r = 0; r < 4; ++r) dst[i0 + q * 4 + r] = accab[r] + off;
        }
    }
}

// ---------- K3: sort (single block, verified r11; float4 b loads) ----------

__global__ __launch_bounds__(1024) void sort_kernel(
        const float* __restrict__ b, float* __restrict__ scal,
        unsigned* __restrict__ offs_g, unsigned short* __restrict__ perm_g,
        float* __restrict__ bsort_g) {
    __shared__ unsigned oh[NBUCK / 2];
    __shared__ unsigned cur[NBUCK / 2];
    __shared__ unsigned short ls[8192];
    __shared__ unsigned wtu[16];
    __shared__ float smn[16], smx[16], sbp[2];
    int t = threadIdx.x, lane = t & 63, wv = t >> 6;
    #pragma unroll
    for (int r = 0; r < 4; ++r) { oh[t + r * 1024] = 0u; cur[t + r * 1024] = 0u; }
    // load b via float4 (thread t owns rows 4t..4t+3 and 4096+4t..)
    float bv[8];
    *(float4*)&bv[0] = ((const float4*)b)[t];
    *(float4*)&bv[4] = ((const float4*)b)[1024 + t];
    float mn = 1e30f, mx = -1e30f;
    #pragma unroll
    for (int r = 0; r < 8; ++r) { mn = fminf(mn, bv[r]); mx = fmaxf(mx, bv[r]); }
    for (int off = 32; off; off >>= 1) {
        mn = fminf(mn, __shfl_down(mn, off));
        mx = fmaxf(mx, __shfl_down(mx, off));
    }
    if (lane == 0) { smn[wv] = mn; smx[wv] = mx; }
    __syncthreads();
    if (t == 0) {
        float gmn = smn[0], gmx = smx[0];
        #pragma unroll
        for (int i = 1; i < 16; ++i) {
            gmn = fminf(gmn, smn[i]); gmx = fmaxf(gmx, smx[i]);
        }
        float range = gmx - gmn;
        float iw = (range > 1e-30f) ? (float)NBUCK / range : 0.f;
        sbp[0] = gmn; sbp[1] = iw;
        scal[4] = gmn; scal[5] = iw;
    }
    __syncthreads();
    float bmin = sbp[0], inv_w = sbp[1];
    int kb[8];
    #pragma unroll
    for (int r = 0; r < 8; ++r) {
        kb[r] = bucket_of(bv[r], bmin, inv_w);
        atomicAdd(&oh[kb[r] >> 1], (kb[r] & 1) ? 0x10000u : 1u);
    }
    __syncthreads();
    unsigned h[8], p = 0;
    #pragma unroll
    for (int w = 0; w < 4; ++w) {
        unsigned word = oh[t * 4 + w];
        p += word & 0xffffu;  h[w * 2]     = p;
        p += word >> 16;      h[w * 2 + 1] = p;
    }
    unsigned v = p;
    #pragma unroll
    for (int d = 1; d < 64; d <<= 1) {
        unsigned u = __shfl_up(v, d);
        if (lane >= d) v += u;
    }
    if (lane == 63) wtu[wv] = v;
    __syncthreads();
    if (t < 16) {
        unsigned w = wtu[t];
        #pragma unroll
        for (int d = 1; d < 16; d <<= 1) {
            unsigned u = __shfl_up(w, d);
            if (t >= d) w += u;
        }
        wtu[t] = w;
    }
    __syncthreads();
    unsigned base = (v - p) + (wv ? wtu[wv - 1] : 0u);
    #pragma unroll
    for (int w = 0; w < 4; ++w) {
        unsigned lo = base + h[w * 2], hi = base + h[w * 2 + 1];
        oh[t * 4 + w] = lo | (hi << 16);
        offs_g[t * 8 + w * 2 + 1] = lo;
        offs_g[t * 8 + w * 2 + 2] = hi;
    }
    if (t == 0) offs_g[0] = 0u;
    __syncthreads();
    #pragma unroll
    for (int r = 0; r < 8; ++r) {
        int j = (r < 4) ? (t * 4 + r) : (4096 + t * 4 + (r - 4));
        int k = kb[r];
        unsigned st = 0u;
        if (k > 0) {
            unsigned word = oh[(k - 1) >> 1];
            st = ((k - 1) & 1) ? (word >> 16) : (word & 0xffffu);
        }
        unsigned old = atomicAdd(&cur[k >> 1], (k & 1) ? 0x10000u : 1u);
        unsigned pos = (k & 1) ? (old >> 16) : (old & 0xffffu);
        ls[st + pos] = (unsigned short)j;
    }
    __syncthreads();
    #pragma unroll
    for (int r = 0; r < 8; ++r) {
        int e = t + r * 1024;
        int j = ls[e];
        perm_g[e] = (unsigned short)j;
        bsort_g[e] = b[j];
    }
}

// ---------- K4: per-segment sums (verified r7/r11, unchanged) ----------

__global__ __launch_bounds__(128) void segsum_kernel(
        const _Float16* __restrict__ g, const unsigned short* __restrict__ perm,
        const float* __restrict__ bsort,
        float* __restrict__ seg1, float* __restrict__ seg2) {
    __shared__ int pj[SEG];
    __shared__ float pb[SEG];
    int s = blockIdx.x, t = threadIdx.x;
    if (t < SEG) { pj[t] = perm[s * SEG + t]; pb[t] = bsort[s * SEG + t]; }
    __syncthreads();
    float a1 = 0.f, a2 = 0.f;
    #pragma unroll
    for (int e = 0; e < SEG; ++e) {
        float gv = (float)g[(size_t)pj[e] * C_INT + t];
        a1 += gv; a2 += pb[e] * gv;
    }
    seg1[s * C_INT + t] = a1;
    seg2[s * C_INT + t] = a2;
}

// ---------- K5: expand to row-granular suffix sums (verified r7/r11, unchanged) ----------

__global__ __launch_bounds__(128) void expand_kernel(
        const _Float16* __restrict__ g, const unsigned short* __restrict__ perm,
        const float* __restrict__ bsort,
        const float* __restrict__ seg1, const float* __restrict__ seg2,
        float* __restrict__ Pr1, float* __restrict__ Pr2) {
    __shared__ int pj[SEG];
    __shared__ float pb[SEG];
    int s = blockIdx.x, t = threadIdx.x;
    if (t < SEG) { pj[t] = perm[s * SEG + t]; pb[t] = bsort[s * SEG + t]; }
    __syncthreads();
    float r1 = 0.f, r2 = 0.f;
    for (int s2 = s + 1; s2 < NSEG; ++s2) {
        r1 += seg1[s2 * C_INT + t];
        r2 += seg2[s2 * C_INT + t];
    }
    #pragma unroll
    for (int e = SEG - 1; e >= 0; --e) {
        float gv = (float)g[(size_t)pj[e] * C_INT + t];
        r1 += gv; r2 += pb[e] * gv;
        size_t idx = (size_t)(s * SEG + e) * C_INT + t;
        Pr1[idx] = r1; Pr2[idx] = r2;
    }
    if (s == NSEG - 1) {
        Pr1[(size_t)8192 * C_INT + t] = 0.f;
        Pr2[(size_t)8192 * C_INT + t] = 0.f;
    }
}

// ---------- K6: per-row output: Pr lookup + direct-broadcast tail (no LDS/syncs) ----------

__global__ __launch_bounds__(128) void out_kernel(
        const float* __restrict__ a, const float* __restrict__ scal,
        const _Float16* __restrict__ g,
        const unsigned* __restrict__ offs, const unsigned short* __restrict__ perm,
        const float* __restrict__ bsort,
        const float* __restrict__ Pr1, const float* __restrict__ Pr2,
        float* __restrict__ out, float inv_n) {
    int i = blockIdx.x, c = threadIdx.x;
    float ai = a[i], thr = -ai;
    float bmin = scal[4], inv_w = scal[5];
    int ki = bucket_of(thr, bmin, inv_w);
    unsigned e0 = offs[ki], e1 = offs[ki + 1];
    size_t base = (size_t)e1 * C_INT + c;
    float acc = ai * Pr1[base] + Pr2[base];
    for (unsigned e = e0; e < e1; ++e) {       // avg ~1 iter (1 elem/bucket)
        float bj = bsort[e];                   // broadcast load (wave-uniform addr)
        if (bj > thr) {
            int j = perm[e];
            acc += (ai + bj) * (float)g[(size_t)j * C_INT + c];
        }
    }
    out[(size_t)i * C_INT + c] = acc * inv_n;
}

// ---------- launch ----------

extern "C" void kernel_launch(void* const* d_in, const int* in_sizes, int n_in,
                              void* d_out, int out_size, void* d_ws, size_t ws_size,
                              hipStream_t stream) {
    const float* x    = (const float*)d_in[0];
    const float* Wg   = (const float*)d_in[1];
    const float* bg   = (const float*)d_in[2];
    const float* Wt   = (const float*)d_in[3];
    const float* bt   = (const float*)d_in[4];
    const float* Wp   = (const float*)d_in[5];
    const float* bp   = (const float*)d_in[6];
    const float* wcat = (const float*)d_in[7];
    float* out = (float*)d_out;
    int n = in_sizes[0] / C_IN;   // 8192

    char* w = (char*)d_ws;
    size_t off = 0;
    auto alloc = [&](size_t bytes) -> void* {
        void* p = w + off;
        off += (bytes + 255) & ~(size_t)255;
        return p;
    };
    float*          ut    = (float*)alloc(C_IN * 4);
    float*          up    = (float*)alloc(C_IN * 4);
    float*          scal  = (float*)alloc(32);
    float*          a     = (float*)alloc((size_t)n * 4);
    float*          b     = (float*)alloc((size_t)n * 4);
    unsigned*       offs  = (unsigned*)alloc((size_t)(NBUCK + 1) * 4);
    unsigned short* perm  = (unsigned short*)alloc((size_t)n * 2);
    float*          bsort = (float*)alloc((size_t)n * 4);
    _Float16*       g     = (_Float16*)alloc((size_t)n * C_INT * 2);
    unsigned short* WgT   = (unsigned short*)alloc((size_t)C_INT * C_IN * 2);
    float*          seg1  = (float*)alloc((size_t)NSEG * C_INT * 4);
    float*          seg2  = (float*)alloc((size_t)NSEG * C_INT * 4);
    float*          Pr1   = (float*)alloc((size_t)(n + 1) * C_INT * 4);
    float*          Pr2   = (float*)alloc((size_t)(n + 1) * C_INT * 4);

    prep_kernel<<<25, 256, 0, stream>>>(Wt, Wp, Wg, wcat, bt, bp, ut, up, scal, WgT);
    gemm_mfma<<<n / 8, 256, 0, stream>>>(x, WgT, bg, ut, up, scal, g, a, b);
    sort_kernel<<<1, 1024, 0, stream>>>(b, scal, offs, perm, bsort);
    segsum_kernel<<<NSEG, 128, 0, stream>>>(g, perm, bsort, seg1, seg2);
    expand_kernel<<<NSEG, 128, 0, stream>>>(g, perm, bsort, seg1, seg2, Pr1, Pr2);
    out_kernel<<<n, 128, 0, stream>>>(a, scal, g, offs, perm, bsort, Pr1, Pr2,
                                      out, 1.0f / (float)n);
}